// Round 9
// baseline (103.406 us; speedup 1.0000x reference)
//
#include <hip/hip_runtime.h>
#include <math.h>

#define NTHR 256
#define B_ 4
#define F_ 512
#define N_ 1024
#define V_ 4
#define NBLK (B_ * F_)              // 2048: one block per (b,f) row (1024 pts)

struct Partial {                    // 64 B, all f32
  float sum_diff2, sum_dist, sum_acc2, cnt;
  float gmin[3], gmax[3], pmin[3], pmax[3];
};

__global__ __launch_bounds__(NTHR, 4) void loss_fused(
    const float* __restrict__ pred, const float* __restrict__ gt,
    const int* __restrict__ vis, const float* __restrict__ P,
    const float* __restrict__ tracks, Partial* __restrict__ partials,
    unsigned int* __restrict__ ticket, float* __restrict__ out)
{
  __shared__ float sP[V_ * 12];
  __shared__ Partial sw[NTHR / 64];
  __shared__ unsigned int sTicket;

  // XCD-bijective swizzle (2048 % 8 == 0): 256 consecutive rows per XCD
  const int bid = ((blockIdx.x & 7) << 8) + (blockIdx.x >> 3);
  const int b = bid >> 9;
  const int f = bid & (F_ - 1);
  const int t = threadIdx.x;

  if (t < V_ * 12) { const int v = t / 12, j = t - v * 12; sP[t] = P[(v * B_ + b) * 12 + j]; }
  __syncthreads();

  const size_t e = ((size_t)bid << 10) + ((size_t)t << 2);  // first point of quad
  const int d1 = (f + 1 < F_) ? N_ : 0;       // clamped neighbor offsets (points)
  const int d2 = (f + 2 < F_) ? 2 * N_ : 0;
  const float am = (f < F_ - 2) ? 1.0f : 0.0f;

  // ================= issue ALL loads (21 x 16B), then fence scheduling ======
  const float4* pp4 = (const float4*)(pred + e * 3);
  const float4 pA = pp4[0], pB = pp4[1], pC = pp4[2];
  const float4* gp4 = (const float4*)(gt + e * 3);
  const float4 gA = gp4[0], gB = gp4[1], gC = gp4[2];
  const int4 vv = *(const int4*)(vis + e);
  const float4* q14 = (const float4*)(pred + (e + d1) * 3);
  const float4 aA = q14[0], aB = q14[1], aC = q14[2];
  const float4* q24 = (const float4*)(pred + (e + d2) * 3);
  const float4 cA = q24[0], cB = q24[1], cC = q24[2];
  const size_t fn2 = (e & ((size_t)F_ * N_ - 1)) << 1;
  const float4* tp0 = (const float4*)(tracks + (((size_t)(0 * B_ + b)) << 20) + fn2);
  const float4* tp1 = (const float4*)(tracks + (((size_t)(1 * B_ + b)) << 20) + fn2);
  const float4* tp2 = (const float4*)(tracks + (((size_t)(2 * B_ + b)) << 20) + fn2);
  const float4* tp3 = (const float4*)(tracks + (((size_t)(3 * B_ + b)) << 20) + fn2);
  const float4 t0a = tp0[0], t0b = tp0[1];
  const float4 t1a = tp1[0], t1b = tp1[1];
  const float4 t2a = tp2[0], t2b = tp2[1];
  const float4 t3a = tp3[0], t3b = tp3[1];

  __builtin_amdgcn_sched_barrier(0);   // loads may not sink below this point

  // ================= compute, ordered by load-return order ==================
  const float px[4] = {pA.x, pA.w, pB.z, pC.y};
  const float py[4] = {pA.y, pB.x, pB.w, pC.z};
  const float pz[4] = {pA.z, pB.y, pC.x, pC.w};

  float pmin[3], pmax[3];
  pmin[0] = fminf(fminf(px[0], px[1]), fminf(px[2], px[3]));
  pmax[0] = fmaxf(fmaxf(px[0], px[1]), fmaxf(px[2], px[3]));
  pmin[1] = fminf(fminf(py[0], py[1]), fminf(py[2], py[3]));
  pmax[1] = fmaxf(fmaxf(py[0], py[1]), fmaxf(py[2], py[3]));
  pmin[2] = fminf(fminf(pz[0], pz[1]), fminf(pz[2], pz[3]));
  pmax[2] = fmaxf(fmaxf(pz[0], pz[1]), fmaxf(pz[2], pz[3]));

  const float gx[4] = {gA.x, gA.w, gB.z, gC.y};
  const float gy[4] = {gA.y, gB.x, gB.w, gC.z};
  const float gz[4] = {gA.z, gB.y, gC.x, gC.w};
  const int vm[4] = {vv.x, vv.y, vv.z, vv.w};

  float sum_diff2 = 0.0f, cntf = 0.0f;
  float gmin[3] = { INFINITY,  INFINITY,  INFINITY};
  float gmax[3] = {-INFINITY, -INFINITY, -INFINITY};
#pragma unroll
  for (int i = 0; i < 4; ++i) {
    const float vmf = vm[i] ? 1.0f : 0.0f;
    const float d0 = px[i] - gx[i], dy1 = py[i] - gy[i], d2f = pz[i] - gz[i];
    sum_diff2 += vmf * (d0 * d0 + dy1 * dy1 + d2f * d2f);
    cntf += vmf;
    gmin[0] = fminf(gmin[0], vm[i] ? gx[i] :  INFINITY);
    gmax[0] = fmaxf(gmax[0], vm[i] ? gx[i] : -INFINITY);
    gmin[1] = fminf(gmin[1], vm[i] ? gy[i] :  INFINITY);
    gmax[1] = fmaxf(gmax[1], vm[i] ? gy[i] : -INFINITY);
    gmin[2] = fminf(gmin[2], vm[i] ? gz[i] :  INFINITY);
    gmax[2] = fmaxf(gmax[2], vm[i] ? gz[i] : -INFINITY);
  }

  float sum_acc2 = 0.0f;
  {
    const float ax[4] = {aA.x, aA.w, aB.z, aC.y};
    const float ay[4] = {aA.y, aB.x, aB.w, aC.z};
    const float az[4] = {aA.z, aB.y, aC.x, aC.w};
    const float cx[4] = {cA.x, cA.w, cB.z, cC.y};
    const float cy[4] = {cA.y, cB.x, cB.w, cC.z};
    const float cz[4] = {cA.z, cB.y, cC.x, cC.w};
#pragma unroll
    for (int i = 0; i < 4; ++i) {
      const float a0 = cx[i] - 2.0f * ax[i] + px[i];
      const float a1 = cy[i] - 2.0f * ay[i] + py[i];
      const float a2 = cz[i] - 2.0f * az[i] + pz[i];
      sum_acc2 += a0 * a0 + a1 * a1 + a2 * a2;
    }
    sum_acc2 *= am;
  }

  float sum_dist = 0.0f;
  {
    const float tx[V_][4] = {{t0a.x, t0a.z, t0b.x, t0b.z},
                             {t1a.x, t1a.z, t1b.x, t1b.z},
                             {t2a.x, t2a.z, t2b.x, t2b.z},
                             {t3a.x, t3a.z, t3b.x, t3b.z}};
    const float ty[V_][4] = {{t0a.y, t0a.w, t0b.y, t0b.w},
                             {t1a.y, t1a.w, t1b.y, t1b.w},
                             {t2a.y, t2a.w, t2b.y, t2b.w},
                             {t3a.y, t3a.w, t3b.y, t3b.w}};
#pragma unroll
    for (int v = 0; v < V_; ++v) {
      const float* Pm = sP + v * 12;
#pragma unroll
      for (int i = 0; i < 4; ++i) {
        const float h0 = Pm[0] * px[i] + Pm[1] * py[i] + Pm[2]  * pz[i] + Pm[3];
        const float h1 = Pm[4] * px[i] + Pm[5] * py[i] + Pm[6]  * pz[i] + Pm[7];
        const float h2 = Pm[8] * px[i] + Pm[9] * py[i] + Pm[10] * pz[i] + Pm[11];
        const float inv = __builtin_amdgcn_rcpf(h2 + 1e-10f);
        const float dx = h0 * inv - tx[v][i];
        const float dy = h1 * inv - ty[v][i];
        sum_dist += dx * dx + dy * dy;
      }
    }
  }

  // ================= wave shuffle tree (deterministic) ======================
#pragma unroll
  for (int o = 32; o > 0; o >>= 1) {
    sum_diff2 += __shfl_down(sum_diff2, o);
    sum_dist  += __shfl_down(sum_dist,  o);
    sum_acc2  += __shfl_down(sum_acc2,  o);
    cntf      += __shfl_down(cntf,      o);
#pragma unroll
    for (int k = 0; k < 3; ++k) {
      gmin[k] = fminf(gmin[k], __shfl_down(gmin[k], o));
      gmax[k] = fmaxf(gmax[k], __shfl_down(gmax[k], o));
      pmin[k] = fminf(pmin[k], __shfl_down(pmin[k], o));
      pmax[k] = fmaxf(pmax[k], __shfl_down(pmax[k], o));
    }
  }

  const int wave = t >> 6, lane = t & 63;
  if (lane == 0) {
    Partial p;
    p.sum_diff2 = sum_diff2; p.sum_dist = sum_dist;
    p.sum_acc2  = sum_acc2;  p.cnt      = cntf;
#pragma unroll
    for (int k = 0; k < 3; ++k) {
      p.gmin[k] = gmin[k]; p.gmax[k] = gmax[k];
      p.pmin[k] = pmin[k]; p.pmax[k] = pmax[k];
    }
    sw[wave] = p;
  }
  __syncthreads();
  if (t == 0) {
    Partial p = sw[0];
#pragma unroll
    for (int w = 1; w < NTHR / 64; ++w) {
      p.sum_diff2 += sw[w].sum_diff2; p.sum_dist += sw[w].sum_dist;
      p.sum_acc2  += sw[w].sum_acc2;  p.cnt      += sw[w].cnt;
#pragma unroll
      for (int k = 0; k < 3; ++k) {
        p.gmin[k] = fminf(p.gmin[k], sw[w].gmin[k]);
        p.gmax[k] = fmaxf(p.gmax[k], sw[w].gmax[k]);
        p.pmin[k] = fminf(p.pmin[k], sw[w].pmin[k]);
        p.pmax[k] = fmaxf(p.pmax[k], sw[w].pmax[k]);
      }
    }
    partials[bid] = p;
    __threadfence();                       // partial visible device-wide
    sTicket = atomicAdd(ticket, 1u);       // device-scope
  }
  __syncthreads();

  // ================= last block finalizes (fixed-order -> deterministic) ====
  if (sTicket == NBLK - 1) {
    __threadfence();
    float fs0 = 0.0f, fs1 = 0.0f, fs2 = 0.0f, fs3 = 0.0f;
    float fgmin[3] = { INFINITY,  INFINITY,  INFINITY};
    float fgmax[3] = {-INFINITY, -INFINITY, -INFINITY};
    float fpmin[3] = { INFINITY,  INFINITY,  INFINITY};
    float fpmax[3] = {-INFINITY, -INFINITY, -INFINITY};
    for (int i = t; i < NBLK; i += NTHR) {
      const Partial p = partials[i];
      fs0 += p.sum_diff2; fs1 += p.sum_dist; fs2 += p.sum_acc2; fs3 += p.cnt;
#pragma unroll
      for (int k = 0; k < 3; ++k) {
        fgmin[k] = fminf(fgmin[k], p.gmin[k]); fgmax[k] = fmaxf(fgmax[k], p.gmax[k]);
        fpmin[k] = fminf(fpmin[k], p.pmin[k]); fpmax[k] = fmaxf(fpmax[k], p.pmax[k]);
      }
    }
#pragma unroll
    for (int o = 32; o > 0; o >>= 1) {
      fs0 += __shfl_down(fs0, o); fs1 += __shfl_down(fs1, o);
      fs2 += __shfl_down(fs2, o); fs3 += __shfl_down(fs3, o);
#pragma unroll
      for (int k = 0; k < 3; ++k) {
        fgmin[k] = fminf(fgmin[k], __shfl_down(fgmin[k], o));
        fgmax[k] = fmaxf(fgmax[k], __shfl_down(fgmax[k], o));
        fpmin[k] = fminf(fpmin[k], __shfl_down(fpmin[k], o));
        fpmax[k] = fmaxf(fpmax[k], __shfl_down(fpmax[k], o));
      }
    }
    if (lane == 0) {
      Partial p;
      p.sum_diff2 = fs0; p.sum_dist = fs1; p.sum_acc2 = fs2; p.cnt = fs3;
#pragma unroll
      for (int k = 0; k < 3; ++k) {
        p.gmin[k] = fgmin[k]; p.gmax[k] = fgmax[k];
        p.pmin[k] = fpmin[k]; p.pmax[k] = fpmax[k];
      }
      sw[wave] = p;
    }
    __syncthreads();
    if (t == 0) {
      Partial p = sw[0];
#pragma unroll
      for (int w = 1; w < NTHR / 64; ++w) {
        p.sum_diff2 += sw[w].sum_diff2; p.sum_dist += sw[w].sum_dist;
        p.sum_acc2  += sw[w].sum_acc2;  p.cnt      += sw[w].cnt;
#pragma unroll
        for (int k = 0; k < 3; ++k) {
          p.gmin[k] = fminf(p.gmin[k], sw[w].gmin[k]);
          p.gmax[k] = fmaxf(p.gmax[k], sw[w].gmax[k]);
          p.pmin[k] = fminf(p.pmin[k], sw[w].pmin[k]);
          p.pmax[k] = fmaxf(p.pmax[k], sw[w].pmax[k]);
        }
      }
      double sr = -INFINITY;
#pragma unroll
      for (int k = 0; k < 3; ++k) sr = fmax(sr, (double)p.gmax[k] - (double)p.gmin[k]);
      sr += 1e-6;
      const double recon = (double)p.sum_diff2 / fmax((double)p.cnt * 3.0, 1.0) / (sr * sr);
      const double ident = (double)p.sum_dist / 224.0 / ((double)V_ * B_ * F_ * N_ * 2.0);
      double st = -INFINITY;
#pragma unroll
      for (int k = 0; k < 3; ++k) st = fmax(st, (double)p.pmax[k] - (double)p.pmin[k]);
      st += 1e-6;
      const double tloss = (double)p.sum_acc2 / ((double)B_ * (F_ - 2) * N_);
      const double temp = tloss / (st * st);
      const double total = recon + ident + 0.5 * temp;
      out[0] = (float)total;
      out[1] = (float)recon;
      out[2] = (float)ident;
      out[3] = (float)temp;
    }
  }
}

extern "C" void kernel_launch(void* const* d_in, const int* in_sizes, int n_in,
                              void* d_out, int out_size, void* d_ws, size_t ws_size,
                              hipStream_t stream) {
  const float* pred   = (const float*)d_in[0];
  const float* gt     = (const float*)d_in[1];
  const int*   vis    = (const int*)d_in[2];
  const float* P      = (const float*)d_in[3];
  const float* tracks = (const float*)d_in[4];
  Partial* partials = (Partial*)d_ws;                      // 2048 * 64 B
  unsigned int* ticket =
      (unsigned int*)((char*)d_ws + NBLK * sizeof(Partial));

  hipMemsetAsync(ticket, 0, sizeof(unsigned int), stream); // graph-capturable
  loss_fused<<<NBLK, NTHR, 0, stream>>>(pred, gt, vis, P, tracks,
                                        partials, ticket, (float*)d_out);
}